// Round 3
// baseline (4503.889 us; speedup 1.0000x reference)
//
#include <hip/hip_runtime.h>

#define TT 4096      // tokens (4*1024)
#define DM 1024      // d_model
#define DF 4096      // d_ff
#define NE 8         // experts
#define BT 8         // tokens per FFN block
#define FC 256       // f-chunk size

// ---------- ws layout (bytes) ----------
// [0, 32)                int cnt[NE]
// [256, 256+128K)        int tok_list[NE*TT]
// [131328, 131328+128K)  float gate_list[NE*TT]
#define TOK_OFF   256
#define GATE_OFF  131328

__device__ __forceinline__ ushort f2bf_rne(float f) {
    unsigned int u = __float_as_uint(f);
    unsigned int r = (u + 0x7fffu + ((u >> 16) & 1u)) >> 16;
    return (ushort)r;
}

// ---------------- init: zero out + cnt (graph-safe, idempotent) ----------------
__global__ __launch_bounds__(256)
void init_kernel(float4* __restrict__ out, int* __restrict__ cnt)
{
    int i = blockIdx.x * 256 + threadIdx.x;
    out[i] = make_float4(0.f, 0.f, 0.f, 0.f);
    if (blockIdx.x == 0 && threadIdx.x < NE) cnt[threadIdx.x] = 0;
}

// ---------------- Router: 1 wave per token ----------------
__global__ __launch_bounds__(256)
void router_kernel(const float* __restrict__ x, const float* __restrict__ Wr,
                   const float* __restrict__ br,
                   int* __restrict__ cnt, int* __restrict__ tok_list,
                   float* __restrict__ gate_list)
{
    const int t    = (blockIdx.x * blockDim.x + threadIdx.x) >> 6;
    const int lane = threadIdx.x & 63;
    if (t >= TT) return;
    const float* xr = x + (size_t)t * DM;

    float acc[NE];
#pragma unroll
    for (int e = 0; e < NE; e++) acc[e] = 0.f;

    for (int i = 0; i < DM / 64; i++) {
        int d = lane + (i << 6);
        float xv = xr[d];
        const float4* wr = (const float4*)(Wr + (size_t)d * NE);  // row d: 8 fp32
        float4 w0 = wr[0], w1 = wr[1];
        acc[0] += xv * w0.x; acc[1] += xv * w0.y;
        acc[2] += xv * w0.z; acc[3] += xv * w0.w;
        acc[4] += xv * w1.x; acc[5] += xv * w1.y;
        acc[6] += xv * w1.z; acc[7] += xv * w1.w;
    }
#pragma unroll
    for (int e = 0; e < NE; e++) {
#pragma unroll
        for (int off = 32; off > 0; off >>= 1)
            acc[e] += __shfl_down(acc[e], off, 64);
    }

    if (lane == 0) {
        float lg[NE];
#pragma unroll
        for (int e = 0; e < NE; e++) lg[e] = acc[e] + br[e];
        // top-2, stable (lowest index wins ties), matching lax.top_k on softmax'd probs
        int i0 = 0;
        for (int e = 1; e < NE; e++) if (lg[e] > lg[i0]) i0 = e;
        int i1 = (i0 == 0) ? 1 : 0;
        for (int e = 0; e < NE; e++) if (e != i0 && lg[e] > lg[i1]) i1 = e;
        // softmax + top-2 renormalize == sigmoid of logit gap (denominators cancel)
        float g0 = 1.f / (1.f + expf(lg[i1] - lg[i0]));
        float g1 = 1.f - g0;
        int p0 = atomicAdd(&cnt[i0], 1);
        if (p0 < TT) {                      // bounds guard (defense-in-depth)
            tok_list[i0 * TT + p0]  = t;
            gate_list[i0 * TT + p0] = g0;
        }
        int p1 = atomicAdd(&cnt[i1], 1);
        if (p1 < TT) {
            tok_list[i1 * TT + p1]  = t;
            gate_list[i1 * TT + p1] = g1;
        }
    }
}

// ---------------- Gathered expert FFN (fp32 VALU, bf16 x-tile in LDS) ----------------
// grid: (TT/BT tiles, NE experts); block: 256 threads
__global__ __launch_bounds__(256)
void ffn_kernel(const float* __restrict__ x,
                const float* __restrict__ W1, const float* __restrict__ b1,
                const float* __restrict__ W2, const float* __restrict__ b2,
                const int* __restrict__ cnt, const int* __restrict__ tok_list,
                const float* __restrict__ gate_list, float* __restrict__ out)
{
    const int e  = blockIdx.y;
    const int n  = min(cnt[e], TT);         // bounds guard
    const int t0 = blockIdx.x * BT;
    if (t0 >= n) return;
    const int nt  = min(BT, n - t0);
    const int tid = threadIdx.x;

    __shared__ ushort xs[BT][DM];   // 16 KB: x rows quantized to bf16
    __shared__ float  hs[BT][FC];   // 8 KB fp32 h chunk
    __shared__ int    toks[BT];
    __shared__ float  gts[BT];

    if (tid < BT) {
        int src = e * TT + t0 + ((tid < nt) ? tid : 0);  // pad with first token
        toks[tid] = tok_list[src];
        gts[tid]  = (tid < nt) ? gate_list[e * TT + t0 + tid] : 0.f;
    }
    __syncthreads();

    // stage x rows: each row = 256 float4; convert to bf16 (RNE)
#pragma unroll
    for (int r = 0; r < BT; r++) {
        float4 v = ((const float4*)(x + (size_t)toks[r] * DM))[tid];
        ushort4 q;
        q.x = f2bf_rne(v.x); q.y = f2bf_rne(v.y);
        q.z = f2bf_rne(v.z); q.w = f2bf_rne(v.w);
        ((ushort4*)xs[r])[tid] = q;
    }

    const float* W1e = W1 + (size_t)e * DM * DF;
    const float* W2e = W2 + (size_t)e * DF * DM;

    float oacc[BT][4];
#pragma unroll
    for (int t = 0; t < BT; t++) {
        oacc[t][0] = 0.f; oacc[t][1] = 0.f; oacc[t][2] = 0.f; oacc[t][3] = 0.f;
    }

    for (int fb = 0; fb < DF; fb += FC) {
        const int f = fb + tid;   // this thread's f column (FC == blockDim)
        float hacc[BT];
#pragma unroll
        for (int t = 0; t < BT; t++) hacc[t] = 0.f;

        __syncthreads();  // xs staged (iter 0) / hs fully consumed (iter >0)

        for (int d = 0; d < DM; d += 8) {
            float wf[8];
#pragma unroll
            for (int j = 0; j < 8; j++)
                wf[j] = W1e[(size_t)(d + j) * DF + f];   // coalesced in f
#pragma unroll
            for (int t = 0; t < BT; t++) {
                uint4 xv = *(const uint4*)&xs[t][d];     // one b128 = 8 bf16
                float x0 = __uint_as_float(xv.x << 16);
                float x1 = __uint_as_float(xv.x & 0xffff0000u);
                float x2 = __uint_as_float(xv.y << 16);
                float x3 = __uint_as_float(xv.y & 0xffff0000u);
                float x4 = __uint_as_float(xv.z << 16);
                float x5 = __uint_as_float(xv.z & 0xffff0000u);
                float x6 = __uint_as_float(xv.w << 16);
                float x7 = __uint_as_float(xv.w & 0xffff0000u);
                hacc[t] += x0 * wf[0]; hacc[t] += x1 * wf[1];
                hacc[t] += x2 * wf[2]; hacc[t] += x3 * wf[3];
                hacc[t] += x4 * wf[4]; hacc[t] += x5 * wf[5];
                hacc[t] += x6 * wf[6]; hacc[t] += x7 * wf[7];
            }
        }
        float b1v = b1[e * DF + f];
#pragma unroll
        for (int t = 0; t < BT; t++)
            hs[t][tid] = fmaxf(hacc[t] + b1v, 0.f);
        __syncthreads();

        // phase 2: thread owns d = tid + 256*j
        for (int fl = 0; fl < FC; fl += 4) {
            float w[4][4];
#pragma unroll
            for (int j = 0; j < 4; j++) {
                const float* wrow = W2e + (size_t)(fb + fl + j) * DM + tid;
                w[j][0] = wrow[0];
                w[j][1] = wrow[256];
                w[j][2] = wrow[512];
                w[j][3] = wrow[768];
            }
#pragma unroll
            for (int t = 0; t < BT; t++) {
                float4 h4 = *(const float4*)&hs[t][fl];
#pragma unroll
                for (int jj = 0; jj < 4; jj++) {
                    oacc[t][jj] += h4.x * w[0][jj];
                    oacc[t][jj] += h4.y * w[1][jj];
                    oacc[t][jj] += h4.z * w[2][jj];
                    oacc[t][jj] += h4.w * w[3][jj];
                }
            }
        }
    }

    // epilogue: out += gate * (y + b2), fp32 atomics straight into d_out
#pragma unroll
    for (int jj = 0; jj < 4; jj++) {
        int d = tid + 256 * jj;
        float b2v = b2[e * DM + d];
        for (int t = 0; t < nt; t++) {
            atomicAdd(&out[(size_t)toks[t] * DM + d], gts[t] * (oacc[t][jj] + b2v));
        }
    }
}

extern "C" void kernel_launch(void* const* d_in, const int* in_sizes, int n_in,
                              void* d_out, int out_size, void* d_ws, size_t ws_size,
                              hipStream_t stream)
{
    const float* x  = (const float*)d_in[0];
    const float* Wr = (const float*)d_in[1];
    const float* br = (const float*)d_in[2];
    const float* W1 = (const float*)d_in[3];
    const float* b1 = (const float*)d_in[4];
    const float* W2 = (const float*)d_in[5];
    const float* b2 = (const float*)d_in[6];
    float* out = (float*)d_out;

    char* ws = (char*)d_ws;
    int*   cnt  = (int*)ws;
    int*   tok  = (int*)(ws + TOK_OFF);
    float* gate = (float*)(ws + GATE_OFF);

    // zero out (TT*DM floats) + cnt via kernel (hipMemsetAsync is NOT reliably
    // captured as a graph node -> round-2 replay divergence)
    init_kernel<<<(TT * DM) / 1024, 256, 0, stream>>>((float4*)out, cnt);

    router_kernel<<<TT / 4, 256, 0, stream>>>(x, Wr, br, cnt, tok, gate);

    dim3 g(TT / BT, NE);
    ffn_kernel<<<g, 256, 0, stream>>>(x, W1, b1, W2, b2, cnt, tok, gate, out);
}

// Round 5
// 828.550 us; speedup vs baseline: 5.4359x; 5.4359x over previous
//
#include <hip/hip_runtime.h>

#define TT 4096      // tokens
#define DM 1024      // d_model
#define DF 4096      // d_ff
#define NE 8         // experts

typedef short bf16x8 __attribute__((ext_vector_type(8)));
typedef float f32x4  __attribute__((ext_vector_type(4)));

// ---------- ws layout (bytes), total ~85.4 MB ----------
#define CNT_OFF    0
#define OFFS_OFF   256
#define POS_OFF    512
#define METAI_OFF  4096                      // int[TT]
#define METAG_OFF  (METAI_OFF + 4*TT)        // float[TT]
#define STOK_OFF   (METAG_OFF + 4*TT)        // int[8320]
#define SGATE_OFF  (STOK_OFF + 4*8320)       // float[8320]
#define XG_OFF     ((SGATE_OFF + 4*8320 + 255) & ~255)   // ushort[8320*1024]
#define H_OFF      (XG_OFF + 8320*1024*2)                // ushort[8320*4096]

// fp32 pair -> packed bf16x2 (RNE): low16 = bf16(a), high16 = bf16(b)
__device__ __forceinline__ unsigned pkbf(float a, float b) {
    unsigned ua = __float_as_uint(a), ub = __float_as_uint(b);
    ua += 0x7fffu + ((ua >> 16) & 1u);
    ub += 0x7fffu + ((ub >> 16) & 1u);
    return __builtin_amdgcn_perm(ub, ua, 0x07060302u);
}

// ---------------- init: zero out + cnt ----------------
__global__ __launch_bounds__(256)
void init_kernel(float4* __restrict__ out, int* __restrict__ cnt)
{
    int i = blockIdx.x * 256 + threadIdx.x;
    out[i] = make_float4(0.f, 0.f, 0.f, 0.f);
    if (blockIdx.x == 0 && threadIdx.x < NE) cnt[threadIdx.x] = 0;
}

// ---------------- Router: 1 wave/token, fp32 exact ----------------
__global__ __launch_bounds__(256)
void router_kernel(const float* __restrict__ x, const float* __restrict__ Wr,
                   const float* __restrict__ br,
                   int* __restrict__ cnt, int* __restrict__ meta_i,
                   float* __restrict__ meta_g)
{
    const int t    = (blockIdx.x * blockDim.x + threadIdx.x) >> 6;
    const int lane = threadIdx.x & 63;
    if (t >= TT) return;
    const float* xr = x + (size_t)t * DM;

    float acc[NE];
#pragma unroll
    for (int e = 0; e < NE; e++) acc[e] = 0.f;
    for (int i = 0; i < DM / 64; i++) {
        int d = lane + (i << 6);
        float xv = xr[d];
        const float4* wr = (const float4*)(Wr + (size_t)d * NE);
        float4 w0 = wr[0], w1 = wr[1];
        acc[0] += xv * w0.x; acc[1] += xv * w0.y;
        acc[2] += xv * w0.z; acc[3] += xv * w0.w;
        acc[4] += xv * w1.x; acc[5] += xv * w1.y;
        acc[6] += xv * w1.z; acc[7] += xv * w1.w;
    }
#pragma unroll
    for (int e = 0; e < NE; e++)
#pragma unroll
        for (int off = 32; off > 0; off >>= 1)
            acc[e] += __shfl_down(acc[e], off, 64);

    if (lane == 0) {
        float lg[NE];
#pragma unroll
        for (int e = 0; e < NE; e++) lg[e] = acc[e] + br[e];
        int i0 = 0;
        for (int e = 1; e < NE; e++) if (lg[e] > lg[i0]) i0 = e;
        int i1 = (i0 == 0) ? 1 : 0;
        for (int e = 0; e < NE; e++) if (e != i0 && lg[e] > lg[i1]) i1 = e;
        float g0 = 1.f / (1.f + expf(lg[i1] - lg[i0]));  // == renormalized top-2 softmax
        atomicAdd(&cnt[i0], 1);
        atomicAdd(&cnt[i1], 1);
        meta_i[t] = i0 | (i1 << 8);
        meta_g[t] = g0;
    }
}

// ---------------- scan: exclusive prefix over 8 counts ----------------
__global__ void scan_kernel(const int* __restrict__ cnt, int* __restrict__ offs,
                            int* __restrict__ pos)
{
    if (threadIdx.x == 0) {
        int o = 0;
        for (int e = 0; e < NE; e++) { offs[e] = o; pos[e] = o; o += cnt[e]; }
    }
}

// ---------------- scatter: slot assign + gather x -> bf16 Xg ----------------
__global__ __launch_bounds__(256)
void scatter_kernel(const float* __restrict__ x, const int* __restrict__ meta_i,
                    const float* __restrict__ meta_g, int* __restrict__ pos,
                    int* __restrict__ slot_tok, float* __restrict__ slot_gate,
                    ushort* __restrict__ Xg)
{
    const int t    = (blockIdx.x * blockDim.x + threadIdx.x) >> 6;
    const int lane = threadIdx.x & 63;
    if (t >= TT) return;
    int s0 = 0, s1 = 0;
    if (lane == 0) {
        int mi = meta_i[t];
        float g0 = meta_g[t];
        int i0 = mi & 0xff, i1 = (mi >> 8) & 0xff;
        s0 = atomicAdd(&pos[i0], 1);
        s1 = atomicAdd(&pos[i1], 1);
        slot_tok[s0] = t; slot_gate[s0] = g0;
        slot_tok[s1] = t; slot_gate[s1] = 1.f - g0;
    }
    s0 = __shfl(s0, 0, 64);
    s1 = __shfl(s1, 0, 64);
    const float4* xr = (const float4*)(x + (size_t)t * DM);
#pragma unroll
    for (int i = 0; i < 4; i++) {
        float4 v = xr[lane + 64 * i];
        uint2 pv = make_uint2(pkbf(v.x, v.y), pkbf(v.z, v.w));
        *(uint2*)(Xg + (size_t)s0 * DM + (lane + 64 * i) * 4) = pv;
        *(uint2*)(Xg + (size_t)s1 * DM + (lane + 64 * i) * 4) = pv;
    }
}

// ---------------- GEMM1: H = relu(Xg @ W1 + b1), bf16 out ----------------
__global__ __launch_bounds__(256)
void gemm1_kernel(const ushort* __restrict__ Xg, const float* __restrict__ W1,
                  const float* __restrict__ b1, const int* __restrict__ cnt,
                  const int* __restrict__ offs, ushort* __restrict__ H)
{
    const int e = blockIdx.z;
    const int n_e = cnt[e];
    const int t0 = blockIdx.y * 128;
    if (t0 >= n_e) return;
    const int ft0 = blockIdx.x * 128;
    const int slot0 = offs[e] + t0;
    const float* W1e = W1 + (size_t)e * DM * DF;

    __shared__ char smem[33792];   // As 16K | Bs 16K ; epilogue: Cb 64x132 f32

    const int tid = threadIdx.x;
    const int l = tid & 63, wid = tid >> 6;
    const int wm = (wid >> 1) * 64, wn = (wid & 1) * 64;
    const int lm = l & 15, q = l >> 4;

    f32x4 acc[4][4];
#pragma unroll
    for (int i = 0; i < 4; i++)
#pragma unroll
        for (int j = 0; j < 4; j++) acc[i][j] = (f32x4){0.f, 0.f, 0.f, 0.f};

    for (int k0 = 0; k0 < DM; k0 += 64) {
        __syncthreads();
        // stage A: 4x 16B chunks/thread, XOR swizzle key=row&7
#pragma unroll
        for (int i = 0; i < 4; i++) {
            int cid = tid + 256 * i;
            int row = cid >> 3, c = cid & 7;
            uint4 v = *(const uint4*)(Xg + (size_t)(slot0 + row) * DM + k0 + c * 8);
            *(uint4*)(smem + row * 128 + ((c ^ (row & 7)) * 16)) = v;
        }
        // stage B: transpose W1[k][f] -> Bs[n][k], fp32->bf16
#pragma unroll
        for (int i = 0; i < 2; i++) {
            int u = tid + 256 * i;
            int n4 = (u & 31) * 4;
            int kg = (u >> 5) * 4;
            const float* src = W1e + (size_t)(k0 + kg) * DF + ft0 + n4;
            float4 r0 = *(const float4*)(src);
            float4 r1 = *(const float4*)(src + DF);
            float4 r2 = *(const float4*)(src + 2 * DF);
            float4 r3 = *(const float4*)(src + 3 * DF);
            const float* p0 = (const float*)&r0; const float* p1 = (const float*)&r1;
            const float* p2 = (const float*)&r2; const float* p3 = (const float*)&r3;
#pragma unroll
            for (int j = 0; j < 4; j++) {
                int n = n4 + j;
                uint2 pv = make_uint2(pkbf(p0[j], p1[j]), pkbf(p2[j], p3[j]));
                int cs = (kg >> 3) ^ ((n >> 1) & 7);
                *(uint2*)(smem + 16384 + n * 128 + cs * 16 + (kg & 4) * 2) = pv;
            }
        }
        __syncthreads();
#pragma unroll
        for (int s = 0; s < 2; s++) {
            bf16x8 af[4], bfr[4];
#pragma unroll
            for (int i = 0; i < 4; i++) {
                int row = wm + i * 16 + lm;
                af[i] = *(const bf16x8*)(smem + row * 128 + ((((s << 2) + q) ^ (row & 7)) * 16));
            }
#pragma unroll
            for (int j = 0; j < 4; j++) {
                int n = wn + j * 16 + lm;
                bfr[j] = *(const bf16x8*)(smem + 16384 + n * 128 + ((((s << 2) + q) ^ ((n >> 1) & 7)) * 16));
            }
#pragma unroll
            for (int i = 0; i < 4; i++)
#pragma unroll
                for (int j = 0; j < 4; j++)
                    acc[i][j] = __builtin_amdgcn_mfma_f32_16x16x32_bf16(af[i], bfr[j], acc[i][j], 0, 0, 0);
        }
    }

    // epilogue: relu(+b1) -> bf16 H, LDS bounce per 64-row half
    float b1v[4];
#pragma unroll
    for (int j = 0; j < 4; j++) b1v[j] = b1[e * DF + ft0 + wn + j * 16 + lm];

    float* Cb = (float*)smem;   // [64][132]
    __syncthreads();
#pragma unroll
    for (int h = 0; h < 2; h++) {
        if ((wid >> 1) == h) {
#pragma unroll
            for (int i = 0; i < 4; i++)
#pragma unroll
                for (int j = 0; j < 4; j++)
#pragma unroll
                    for (int r = 0; r < 4; r++) {
                        int lrow = i * 16 + q * 4 + r;
                        int col = wn + j * 16 + lm;
                        Cb[lrow * 132 + col] = fmaxf(acc[i][j][r] + b1v[j], 0.f);
                    }
        }
        __syncthreads();
        {
            int row = tid >> 2, seg = tid & 3;
            // GUARD: partial tiles must not write H rows of the next expert's
            // compact slots (round-4 bug: clobbered neighbor-expert H).
            if (t0 + h * 64 + row < n_e) {
                size_t hbase = (size_t)(slot0 + h * 64 + row) * DF + ft0 + seg * 32;
#pragma unroll
                for (int i = 0; i < 4; i++) {
                    float4 a = *(const float4*)&Cb[row * 132 + seg * 32 + i * 8];
                    float4 b = *(const float4*)&Cb[row * 132 + seg * 32 + i * 8 + 4];
                    uint4 o;
                    o.x = pkbf(a.x, a.y); o.y = pkbf(a.z, a.w);
                    o.z = pkbf(b.x, b.y); o.w = pkbf(b.z, b.w);
                    *(uint4*)(H + hbase + i * 8) = o;
                }
            }
        }
        __syncthreads();
    }
}

// ---------------- GEMM2: out += gate*(H @ W2 + b2), K split x2 ----------------
__global__ __launch_bounds__(256)
void gemm2_kernel(const ushort* __restrict__ H, const float* __restrict__ W2,
                  const float* __restrict__ b2, const int* __restrict__ cnt,
                  const int* __restrict__ offs, const int* __restrict__ slot_tok,
                  const float* __restrict__ slot_gate, float* __restrict__ out)
{
    const int e  = blockIdx.z >> 1;
    const int kz = blockIdx.z & 1;
    const int n_e = cnt[e];
    const int t0 = blockIdx.y * 128;
    if (t0 >= n_e) return;
    const int nt0 = blockIdx.x * 128;
    const int slot0 = offs[e] + t0;
    const float* W2e = W2 + (size_t)e * DF * DM;

    __shared__ char smem[32768];

    const int tid = threadIdx.x;
    const int l = tid & 63, wid = tid >> 6;
    const int wm = (wid >> 1) * 64, wn = (wid & 1) * 64;
    const int lm = l & 15, q = l >> 4;

    f32x4 acc[4][4];
#pragma unroll
    for (int i = 0; i < 4; i++)
#pragma unroll
        for (int j = 0; j < 4; j++) acc[i][j] = (f32x4){0.f, 0.f, 0.f, 0.f};

    const int kbeg = kz * (DF / 2);
    for (int k0 = kbeg; k0 < kbeg + DF / 2; k0 += 64) {
        __syncthreads();
#pragma unroll
        for (int i = 0; i < 4; i++) {
            int cid = tid + 256 * i;
            int row = cid >> 3, c = cid & 7;
            uint4 v = *(const uint4*)(H + (size_t)(slot0 + row) * DF + k0 + c * 8);
            *(uint4*)(smem + row * 128 + ((c ^ (row & 7)) * 16)) = v;
        }
#pragma unroll
        for (int i = 0; i < 2; i++) {
            int u = tid + 256 * i;
            int n4 = (u & 31) * 4;
            int kg = (u >> 5) * 4;
            const float* src = W2e + (size_t)(k0 + kg) * DM + nt0 + n4;
            float4 r0 = *(const float4*)(src);
            float4 r1 = *(const float4*)(src + DM);
            float4 r2 = *(const float4*)(src + 2 * DM);
            float4 r3 = *(const float4*)(src + 3 * DM);
            const float* p0 = (const float*)&r0; const float* p1 = (const float*)&r1;
            const float* p2 = (const float*)&r2; const float* p3 = (const float*)&r3;
#pragma unroll
            for (int j = 0; j < 4; j++) {
                int n = n4 + j;
                uint2 pv = make_uint2(pkbf(p0[j], p1[j]), pkbf(p2[j], p3[j]));
                int cs = (kg >> 3) ^ ((n >> 1) & 7);
                *(uint2*)(smem + 16384 + n * 128 + cs * 16 + (kg & 4) * 2) = pv;
            }
        }
        __syncthreads();
#pragma unroll
        for (int s = 0; s < 2; s++) {
            bf16x8 af[4], bfr[4];
#pragma unroll
            for (int i = 0; i < 4; i++) {
                int row = wm + i * 16 + lm;
                af[i] = *(const bf16x8*)(smem + row * 128 + ((((s << 2) + q) ^ (row & 7)) * 16));
            }
#pragma unroll
            for (int j = 0; j < 4; j++) {
                int n = wn + j * 16 + lm;
                bfr[j] = *(const bf16x8*)(smem + 16384 + n * 128 + ((((s << 2) + q) ^ ((n >> 1) & 7)) * 16));
            }
#pragma unroll
            for (int i = 0; i < 4; i++)
#pragma unroll
                for (int j = 0; j < 4; j++)
                    acc[i][j] = __builtin_amdgcn_mfma_f32_16x16x32_bf16(af[i], bfr[j], acc[i][j], 0, 0, 0);
        }
    }

    float b2v[4];
#pragma unroll
    for (int j = 0; j < 4; j++)
        b2v[j] = (kz == 0) ? b2[e * DM + nt0 + wn + j * 16 + lm] : 0.f;

#pragma unroll
    for (int i = 0; i < 4; i++)
#pragma unroll
        for (int r = 0; r < 4; r++) {
            int mrow = wm + i * 16 + q * 4 + r;
            if (t0 + mrow < n_e) {
                int tok = slot_tok[slot0 + mrow];
                float g  = slot_gate[slot0 + mrow];
                float* orow = out + (size_t)tok * DM + nt0;
#pragma unroll
                for (int j = 0; j < 4; j++)
                    atomicAdd(&orow[wn + j * 16 + lm], g * (acc[i][j][r] + b2v[j]));
            }
        }
}

extern "C" void kernel_launch(void* const* d_in, const int* in_sizes, int n_in,
                              void* d_out, int out_size, void* d_ws, size_t ws_size,
                              hipStream_t stream)
{
    const float* x  = (const float*)d_in[0];
    const float* Wr = (const float*)d_in[1];
    const float* br = (const float*)d_in[2];
    const float* W1 = (const float*)d_in[3];
    const float* b1 = (const float*)d_in[4];
    const float* W2 = (const float*)d_in[5];
    const float* b2 = (const float*)d_in[6];
    float* out = (float*)d_out;

    char* ws = (char*)d_ws;
    int*    cnt   = (int*)(ws + CNT_OFF);
    int*    offs  = (int*)(ws + OFFS_OFF);
    int*    pos   = (int*)(ws + POS_OFF);
    int*    metaI = (int*)(ws + METAI_OFF);
    float*  metaG = (float*)(ws + METAG_OFF);
    int*    stok  = (int*)(ws + STOK_OFF);
    float*  sgate = (float*)(ws + SGATE_OFF);
    ushort* Xg    = (ushort*)(ws + XG_OFF);
    ushort* H     = (ushort*)(ws + H_OFF);

    init_kernel<<<(TT * DM) / 1024, 256, 0, stream>>>((float4*)out, cnt);
    router_kernel<<<TT / 4, 256, 0, stream>>>(x, Wr, br, cnt, metaI, metaG);
    scan_kernel<<<1, 64, 0, stream>>>(cnt, offs, pos);
    scatter_kernel<<<TT / 4, 256, 0, stream>>>(x, metaI, metaG, pos, stok, sgate, Xg);

    gemm1_kernel<<<dim3(DF / 128, 32, NE), 256, 0, stream>>>(Xg, W1, b1, cnt, offs, H);
    gemm2_kernel<<<dim3(DM / 128, 32, NE * 2), 256, 0, stream>>>(H, W2, b2, cnt, offs,
                                                                 stok, sgate, out);
}